// Round 2
// baseline (110.233 us; speedup 1.0000x reference)
//
#include <hip/hip_runtime.h>

// Conv1d: out[b,c,i] = sum_{k=0}^{127} x[b,c,i+k] * w[k]
// B=32, C=512, L=4096, KL=128 -> rows=16384, Lo=3969.
//
// bf16 MFMA band-matrix conv, 2 rows per block, single barrier.
//   D[m][n] = sum_k A[m][k]*Bband[k][n], A[m][k]=x[i0+16m+k] (k=0..159),
//   Bband[k][n] = w[k-n] if 0<=k-n<128 else 0.
// bfrag computed per-lane directly from global w (no bandT LDS, no 2nd barrier).
// Memory-bound: ~528 MB HBM -> floor ~84 us @ 6.3 TB/s.

#define NROWS 16384
#define LIN   4096
#define KLEN  128
#define LOUT  3969           // LIN - KLEN + 1
#define KTOT  160            // band K extent
#define NSTEP 5              // KTOT / 32
#define XELEMS (LIN + KTOT)  // 4256 (row + zero tail)
#define RPB   2              // rows per block

typedef __attribute__((ext_vector_type(8))) short bf16x8;
typedef __attribute__((ext_vector_type(4))) float f32x4;

__device__ __forceinline__ unsigned short f2bf(float f) {
    // round-to-nearest-even fp32 -> bf16 (inputs finite)
    unsigned int u = __float_as_uint(f);
    u += 0x7FFFu + ((u >> 16) & 1u);
    return (unsigned short)(u >> 16);
}

__global__ __launch_bounds__(256, 6)
void conv1d_mfma(const float* __restrict__ x, const float* __restrict__ w,
                 float* __restrict__ out) {
    __shared__ __align__(16) unsigned short xs[RPB][XELEMS];  // 17024 B

    const int t = threadIdx.x;
    const long long row0 = (long long)blockIdx.x * RPB;

    const int lane = t & 63;
    const int g    = lane >> 4;   // 0..3
    const int nn   = lane & 15;   // 0..15
    const int wv   = t >> 6;      // wave 0..3

    // ---- issue ALL x loads first (8 x float4 in flight per thread) ----
    float4 v[RPB][4];
    #pragma unroll
    for (int r = 0; r < RPB; ++r) {
        const float* xr = x + (row0 + r) * LIN;
        #pragma unroll
        for (int j = 0; j < 4; ++j)
            v[r][j] = *reinterpret_cast<const float4*>(xr + 4 * (t + 256 * j));
    }

    // ---- B fragments straight from global w (L1-hot), overlaps x latency ----
    // bfrag[kb][j] = w[kb*32 + 8g + j - nn] (0 if out of [0,128))
    bf16x8 bfrag[NSTEP];
    #pragma unroll
    for (int kb = 0; kb < NSTEP; ++kb) {
        #pragma unroll
        for (int j = 0; j < 8; ++j) {
            const int d  = kb * 32 + 8 * g + j - nn;
            const int dc = d < 0 ? 0 : (d > KLEN - 1 ? KLEN - 1 : d);
            float val = w[dc];
            if ((unsigned)d >= (unsigned)KLEN) val = 0.f;
            bfrag[kb][j] = (short)f2bf(val);
        }
    }

    // ---- convert + stage into LDS ----
    #pragma unroll
    for (int r = 0; r < RPB; ++r) {
        #pragma unroll
        for (int j = 0; j < 4; ++j) {
            const int e = 4 * (t + 256 * j);
            ushort4 p;
            p.x = f2bf(v[r][j].x); p.y = f2bf(v[r][j].y);
            p.z = f2bf(v[r][j].z); p.w = f2bf(v[r][j].w);
            *reinterpret_cast<ushort4*>(&xs[r][e]) = p;
        }
    }
    // zero the 160-elem tails (40 ushort4 per row)
    if (t < 40) {
        ushort4 z; z.x = 0; z.y = 0; z.z = 0; z.w = 0;
        *reinterpret_cast<ushort4*>(&xs[0][LIN + 4 * t]) = z;
    } else if (t >= 128 && t < 168) {
        ushort4 z; z.x = 0; z.y = 0; z.z = 0; z.w = 0;
        *reinterpret_cast<ushort4*>(&xs[1][LIN + 4 * (t - 128)]) = z;
    }
    __syncthreads();   // the only barrier

    // ---- 2 rows x 16 tiles (4 waves x 4 iters each) ----
    #pragma unroll
    for (int r = 0; r < RPB; ++r) {
        float* outr = out + (row0 + r) * LOUT;
        #pragma unroll
        for (int it = 0; it < 4; ++it) {
            const int i0 = 256 * (wv + 4 * it);
            const unsigned short* abase = &xs[r][i0 + 16 * nn + 8 * g];
            f32x4 acc = {0.f, 0.f, 0.f, 0.f};
            #pragma unroll
            for (int kb = 0; kb < NSTEP; ++kb) {
                const bf16x8 afrag = *reinterpret_cast<const bf16x8*>(abase + 32 * kb);
                acc = __builtin_amdgcn_mfma_f32_16x16x32_bf16(afrag, bfrag[kb], acc, 0, 0, 0);
            }
            // D: col n = lane&15, row m = 4*(lane>>4) + rr
            #pragma unroll
            for (int rr = 0; rr < 4; ++rr) {
                const int oi = i0 + 64 * g + 16 * rr + nn;
                if (oi < LOUT) outr[oi] = acc[rr];
            }
        }
    }
}

extern "C" void kernel_launch(void* const* d_in, const int* in_sizes, int n_in,
                              void* d_out, int out_size, void* d_ws, size_t ws_size,
                              hipStream_t stream) {
    const float* x = (const float*)d_in[0];
    const float* w = (const float*)d_in[1];
    float* o = (float*)d_out;
    hipLaunchKernelGGL(conv1d_mfma, dim3(NROWS / RPB), dim3(256), 0, stream, x, w, o);
}